// Round 1
// baseline (459.883 us; speedup 1.0000x reference)
//
#include <hip/hip_runtime.h>
#include <hip/hip_bf16.h>

// MS-SSIM + L1 loss. B=128, H=W=384, fp32. Levels k in {1,2,4,7}, box conv
// with zero padding p=k//2 (NOTE: even k -> output is (H+1)x(W+1) = 385x385).
// out = 0.84*(1 - prod_k mean(S_k)) + 0.16*mean(|box7(X)-box7(Y)|)

#define HH 384
#define WW 384
#define BB 128
#define TILE_W 256

// d_ws layout: acc[0..3] = per-level S sums (double), acc[4] = l1 sum (double)

__global__ void zero_acc_kernel(double* acc) {
    if (threadIdx.x < 5) acc[threadIdx.x] = 0.0;
}

template <int K, bool WITH_L1>
__global__ __launch_bounds__(256) void ssim_level_kernel(
    const float* __restrict__ X, const float* __restrict__ Y,
    const float* __restrict__ dr, double* __restrict__ acc,
    int level_idx, int band_h) {
    constexpr int P  = K / 2;
    constexpr int Wo = WW + 2 * P - K + 1;   // output width == height
    constexpr int LW = TILE_W + K - 1;       // staged row width (<=262)

    const int b  = blockIdx.z;
    const int j0 = blockIdx.x * TILE_W;
    const int i0 = blockIdx.y * band_h;
    int i_end = i0 + band_h; if (i_end > Wo) i_end = Wo;
    if (i0 >= i_end) return;

    const float drb = dr[b];
    const float C1 = (0.01f * drb) * (0.01f * drb);
    const float C2 = (0.03f * drb) * (0.03f * drb);

    const float* __restrict__ Xb = X + (size_t)b * HH * WW;
    const float* __restrict__ Yb = Y + (size_t)b * HH * WW;

    __shared__ float sX[LW + 2];
    __shared__ float sY[LW + 2];
    __shared__ float red[256];

    const int t = threadIdx.x;
    const int j = j0 + t;
    const bool jvalid = (j < Wo);

    // vertical ring buffers (statically indexed via K-unrolled phase loop)
    float rx[K], ry[K], rxx[K], ryy[K], rxy[K];
#pragma unroll
    for (int q = 0; q < K; ++q) { rx[q]=0.f; ry[q]=0.f; rxx[q]=0.f; ryy[q]=0.f; rxy[q]=0.f; }
    float csx=0.f, csy=0.f, csxx=0.f, csyy=0.f, csxy=0.f;
    float ssum = 0.f, l1s = 0.f;

    const int u0     = i0 - P;
    const int u_last = i_end - 1 + (K - 1) - P;
    const int c0     = j0 - P;
    constexpr float inv = 1.0f / (float)(K * K);

    for (int base = u0; base <= u_last; base += K) {
#pragma unroll
        for (int ph = 0; ph < K; ++ph) {
            const int u = base + ph;
            if (u > u_last) break;
            const bool rowvalid = (u >= 0) && (u < HH);
            if (rowvalid) {
                const float* xr = Xb + (size_t)u * WW;
                const float* yr = Yb + (size_t)u * WW;
                for (int idx = t; idx < LW; idx += 256) {
                    const int c = c0 + idx;
                    const bool cv = (c >= 0) && (c < WW);
                    sX[idx] = cv ? xr[c] : 0.0f;
                    sY[idx] = cv ? yr[c] : 0.0f;
                }
            }
            __syncthreads();
            float hx=0.f, hy=0.f, hxx=0.f, hyy=0.f, hxy=0.f;
            if (rowvalid) {
#pragma unroll
                for (int d = 0; d < K; ++d) {
                    const float x = sX[t + d];
                    const float y = sY[t + d];
                    hx += x; hy += y;
                    hxx = fmaf(x, x, hxx);
                    hyy = fmaf(y, y, hyy);
                    hxy = fmaf(x, y, hxy);
                }
            }
            csx  += hx  - rx[ph];  rx[ph]  = hx;
            csy  += hy  - ry[ph];  ry[ph]  = hy;
            csxx += hxx - rxx[ph]; rxx[ph] = hxx;
            csyy += hyy - ryy[ph]; ryy[ph] = hyy;
            csxy += hxy - rxy[ph]; rxy[ph] = hxy;

            const int i = u - (K - 1) + P;   // completed output row
            if (i >= i0 && jvalid) {
                const float ux = csx * inv, uy = csy * inv;
                const float uxx = csxx * inv, uyy = csyy * inv, uxy = csxy * inv;
                const float vx  = uxx - ux * ux;
                const float vy  = uyy - uy * uy;
                const float vxy = uxy - ux * uy;
                const float A1 = 2.f * ux * uy + C1;
                const float A2 = 2.f * vxy + C2;
                const float B1 = ux * ux + uy * uy + C1;
                const float B2 = vx + vy + C2;
                ssum += (A1 * A2) / (B1 * B2);
                if (WITH_L1) l1s += fabsf(ux - uy);
            }
            __syncthreads();   // protect LDS before next row's staging
        }
    }

    // block reduction (fp32 partials are small: <= band_h values <= ~1.1 each)
    red[t] = ssum;
    __syncthreads();
    for (int s = 128; s > 0; s >>= 1) {
        if (t < s) red[t] += red[t + s];
        __syncthreads();
    }
    if (t == 0) atomicAdd(&acc[level_idx], (double)red[0]);

    if (WITH_L1) {
        __syncthreads();
        red[t] = l1s;
        __syncthreads();
        for (int s = 128; s > 0; s >>= 1) {
            if (t < s) red[t] += red[t + s];
            __syncthreads();
        }
        if (t == 0) atomicAdd(&acc[4], (double)red[0]);
    }
}

__global__ void finalize_kernel(const double* __restrict__ acc, float* __restrict__ out) {
    const double n384 = (double)BB * 384.0 * 384.0;
    const double n385 = (double)BB * 385.0 * 385.0;
    const double m = (acc[0] / n384) * (acc[1] / n385) * (acc[2] / n385) * (acc[3] / n384);
    const double l1 = acc[4] / n384;
    out[0] = (float)(0.84 * (1.0 - m) + 0.16 * l1);
}

extern "C" void kernel_launch(void* const* d_in, const int* in_sizes, int n_in,
                              void* d_out, int out_size, void* d_ws, size_t ws_size,
                              hipStream_t stream) {
    const float* X  = (const float*)d_in[0];
    const float* Y  = (const float*)d_in[1];
    const float* dr = (const float*)d_in[2];
    float* out = (float*)d_out;
    double* acc = (double*)d_ws;

    zero_acc_kernel<<<1, 64, 0, stream>>>(acc);

    const int NBANDS = 8;
    // Wo=384 levels: band 48; Wo=385 levels: band 49
    {
        dim3 grid(2, NBANDS, BB);
        ssim_level_kernel<1, false><<<grid, 256, 0, stream>>>(X, Y, dr, acc, 0, 48);
        ssim_level_kernel<2, false><<<grid, 256, 0, stream>>>(X, Y, dr, acc, 1, 49);
        ssim_level_kernel<4, false><<<grid, 256, 0, stream>>>(X, Y, dr, acc, 2, 49);
        ssim_level_kernel<7, true ><<<grid, 256, 0, stream>>>(X, Y, dr, acc, 3, 48);
    }

    finalize_kernel<<<1, 1, 0, stream>>>(acc, out);
}